// Round 1
// baseline (1588.889 us; speedup 1.0000x reference)
//
#include <hip/hip_runtime.h>
#include <math.h>

#define NPTS 4096
#define CC 0.7213475204444817f   // log2(e)/2 : exp(-s^2/2) = 2^(-CC*s^2)

__device__ __forceinline__ void gload_lds16(const float* g, float* l) {
  __builtin_amdgcn_global_load_lds(
      (const __attribute__((address_space(1))) void*)g,
      (__attribute__((address_space(3))) void*)l, 16, 0, 0);
}

// ---------------- feature MLP: coords[B,N,3] -> outT[b][h][n] (transposed) ----------------
__global__ __launch_bounds__(256) void feat_kernel(
    const float* __restrict__ coords, const float* __restrict__ W1,
    const float* __restrict__ b1, const float* __restrict__ W2,
    const float* __restrict__ b2, float* __restrict__ outT, int npts)
{
  __shared__ float sW1[3 * 64], sb1[64], sW2[64 * 64], sb2[64];
  const int tid = threadIdx.x;
  for (int i = tid; i < 192; i += 256) sW1[i] = W1[i];
  if (tid < 64) { sb1[tid] = b1[tid]; sb2[tid] = b2[tid]; }
  for (int i = tid; i < 4096; i += 256) sW2[i] = W2[i];
  __syncthreads();

  const int p  = blockIdx.x * 64 + (tid & 63);   // point index (consecutive threads -> consecutive n)
  const int qh = (tid >> 6) * 16;                // h-quarter handled by this thread
  if (p >= npts) return;
  const float c0 = coords[p * 3 + 0], c1 = coords[p * 3 + 1], c2 = coords[p * 3 + 2];

  float hid[64];
  #pragma unroll
  for (int j = 0; j < 64; ++j)
    hid[j] = fmaxf(0.f, fmaf(c0, sW1[j], fmaf(c1, sW1[64 + j], fmaf(c2, sW1[128 + j], sb1[j]))));

  float acc[16];
  #pragma unroll
  for (int h = 0; h < 16; ++h) acc[h] = sb2[qh + h];
  for (int j = 0; j < 64; ++j) {
    const float hj = hid[j];
    const float4* wrow = (const float4*)&sW2[j * 64 + qh];
    #pragma unroll
    for (int hq = 0; hq < 4; ++hq) {
      float4 wv = wrow[hq];
      acc[hq * 4 + 0] = fmaf(hj, wv.x, acc[hq * 4 + 0]);
      acc[hq * 4 + 1] = fmaf(hj, wv.y, acc[hq * 4 + 1]);
      acc[hq * 4 + 2] = fmaf(hj, wv.z, acc[hq * 4 + 2]);
      acc[hq * 4 + 3] = fmaf(hj, wv.w, acc[hq * 4 + 3]);
    }
  }
  const int b = p / NPTS, n = p % NPTS;
  #pragma unroll
  for (int h = 0; h < 16; ++h)
    outT[(size_t)(b * 64 + qh + h) * NPTS + n] = acc[h];
}

// ---------------- Vo kernel: Vo[b,n] = MLP_v(values)[b,n,:] . Wo ----------------
__global__ __launch_bounds__(256) void vo_kernel(
    const float* __restrict__ values, const float* __restrict__ Wv1,
    const float* __restrict__ bv1, const float* __restrict__ Wv2,
    const float* __restrict__ bv2, const float* __restrict__ Wo,
    float* __restrict__ VoOut, int npts)
{
  __shared__ float sWvO[64], sW1[64], sb1[64], sc0;
  const int tid = threadIdx.x;
  if (tid < 64) {
    float a = 0.f;
    for (int h = 0; h < 64; ++h) a = fmaf(Wv2[tid * 64 + h], Wo[h], a);
    sWvO[tid] = a;
    sW1[tid] = Wv1[tid];
    sb1[tid] = bv1[tid];
  } else if (tid == 64) {
    float a = 0.f;
    for (int h = 0; h < 64; ++h) a = fmaf(bv2[h], Wo[h], a);
    sc0 = a;
  }
  __syncthreads();
  const int p = blockIdx.x * 256 + tid;
  if (p >= npts) return;
  const float v = values[p];
  float a = sc0;
  #pragma unroll 8
  for (int j = 0; j < 64; ++j)
    a = fmaf(fmaxf(0.f, fmaf(v, sW1[j], sb1[j])), sWvO[j], a);
  VoOut[p] = a;
}

// ---------------- main attention kernel ----------------
// grid: B*64 blocks (one 64-m tile each), 512 threads (8 waves).
// Each wave owns a 64-n slice per n-iteration; K chunks (8 h-rows x 64 n) stream
// through wave-private LDS double buffers via global_load_lds + counted vmcnt.
__global__ __launch_bounds__(512, 2) void attn_kernel(
    const float* __restrict__ Kt, const float* __restrict__ Qt,
    const float* __restrict__ Vo, const float* __restrict__ bo,
    float* __restrict__ out)
{
  __shared__ float Qs[64 * 64];      // [h][m_local]  16 KB (reused for stats at the end)
  __shared__ float Vos[NPTS];        // Vo for this b 16 KB
  __shared__ float Ks[8][2][512];    // [wave][buf][h_local*64 + n_local] 32 KB

  const int b    = blockIdx.x >> 6;
  const int m0   = (blockIdx.x & 63) << 6;
  const int tid  = threadIdx.x;
  const int w    = tid >> 6;
  const int lane = tid & 63;
  const int lm = lane >> 3, ln = lane & 7;

  const float* __restrict__ KtB = Kt + (size_t)b * 64 * NPTS;
  const float* __restrict__ QtB = Qt + (size_t)b * 64 * NPTS;
  const float* __restrict__ VoB = Vo + (size_t)b * NPTS;

  { // stage Q tile and full Vo row into LDS (coalesced float4)
    const int h = tid >> 3, c8 = (tid & 7) * 8;
    *(float4*)&Qs[h * 64 + c8]     = *(const float4*)&QtB[(size_t)h * NPTS + m0 + c8];
    *(float4*)&Qs[h * 64 + c8 + 4] = *(const float4*)&QtB[(size_t)h * NPTS + m0 + c8 + 4];
    *(float4*)&Vos[tid * 8]     = *(const float4*)&VoB[tid * 8];
    *(float4*)&Vos[tid * 8 + 4] = *(const float4*)&VoB[tid * 8 + 4];
  }
  __syncthreads();   // drains vmcnt too -> clean counting below

  float acc[64];
  float Mt[8], num[8], den[8];
  #pragma unroll
  for (int x = 0; x < 64; ++x) acc[x] = 0.f;
  #pragma unroll
  for (int j = 0; j < 8; ++j) { Mt[j] = __builtin_inff(); num[j] = 0.f; den[j] = 0.f; }

  const int noff = w * 64 + (lane & 15) * 4;  // per-lane n column for staging
  const int hrow = lane >> 4;                 // 0..3: row within a 4-row staging instr

  // chunk c: h = (c&7)*8 + {0..7}, n base = (c>>3)*512 + w*64 ; 2 glds instrs of 1KB
  #define ISSUE_K(c_) do { \
    const int I_ = (c_) >> 3, cc_ = (c_) & 7; \
    const float* s_ = KtB + (size_t)(cc_ * 8 + hrow) * NPTS + I_ * 512 + noff; \
    float* d_ = &Ks[w][(c_) & 1][0]; \
    gload_lds16(s_, d_); \
    gload_lds16(s_ + 4 * NPTS, d_ + 256); \
  } while (0)

  ISSUE_K(0);
  ISSUE_K(1);

  for (int I = 0; I < 8; ++I) {          // n-iterations (512 n each)
    #pragma unroll
    for (int cc = 0; cc < 8; ++cc) {     // h-chunks (8 rows each)
      const int c = I * 8 + cc;
      if (c < 63) asm volatile("s_waitcnt vmcnt(2)" ::: "memory");
      else        asm volatile("s_waitcnt vmcnt(0)" ::: "memory");
      __builtin_amdgcn_sched_barrier(0);
      const float* __restrict__ Kw = &Ks[w][cc & 1][ln * 8];
      const float* __restrict__ Qh = &Qs[(cc * 8) * 64 + lm * 8];
      #pragma unroll
      for (int hh = 0; hh < 8; ++hh) {
        float q[8], k[8];
        *(float4*)&q[0] = *(const float4*)(Qh + hh * 64);
        *(float4*)&q[4] = *(const float4*)(Qh + hh * 64 + 4);
        *(float4*)&k[0] = *(const float4*)(Kw + hh * 64);
        *(float4*)&k[4] = *(const float4*)(Kw + hh * 64 + 4);
        #pragma unroll
        for (int j = 0; j < 8; ++j) {
          #pragma unroll
          for (int i = 0; i < 8; ++i)
            acc[j * 8 + i] += fabsf(k[i] - q[j]);   // v_sub + v_add |src|
        }
      }
      if (c + 2 < 64) ISSUE_K(c + 2);
    }

    { // epilogue for iteration I: online softmax update (min of t = s^2)
      float vo[8];
      const int vb = I * 512 + w * 64 + ln * 8;
      *(float4*)&vo[0] = *(const float4*)&Vos[vb];
      *(float4*)&vo[4] = *(const float4*)&Vos[vb + 4];
      #pragma unroll
      for (int j = 0; j < 8; ++j) {
        float t[8];
        #pragma unroll
        for (int i = 0; i < 8; ++i) t[i] = acc[j * 8 + i] * acc[j * 8 + i];
        float rmin = fminf(fminf(fminf(t[0], t[1]), fminf(t[2], t[3])),
                           fminf(fminf(t[4], t[5]), fminf(t[6], t[7])));
        rmin = fminf(rmin, __shfl_xor(rmin, 1));
        rmin = fminf(rmin, __shfl_xor(rmin, 2));
        rmin = fminf(rmin, __shfl_xor(rmin, 4));
        const float nM = fminf(Mt[j], rmin);
        const float sc = __builtin_amdgcn_exp2f(CC * (nM - Mt[j])); // inf start -> 0
        num[j] *= sc; den[j] *= sc; Mt[j] = nM;
        const float base = CC * nM;
        #pragma unroll
        for (int i = 0; i < 8; ++i) {
          const float wgt = __builtin_amdgcn_exp2f(fmaf(-CC, t[i], base));
          den[j] += wgt;
          num[j] = fmaf(wgt, vo[i], num[j]);
          acc[j * 8 + i] = 0.f;
        }
      }
    }
  }

  // reduce num/den over the 8 ln-lanes sharing each m (Mt already uniform)
  #pragma unroll
  for (int j = 0; j < 8; ++j) {
    #pragma unroll
    for (int off = 1; off < 8; off <<= 1) {
      num[j] += __shfl_xor(num[j], off);
      den[j] += __shfl_xor(den[j], off);
    }
  }
  __syncthreads();                 // everyone done reading Qs/Ks
  if (ln == 0) {
    #pragma unroll
    for (int j = 0; j < 8; ++j) {
      const int ml = lm * 8 + j;
      Qs[(w * 64 + ml) * 3 + 0] = Mt[j];
      Qs[(w * 64 + ml) * 3 + 1] = num[j];
      Qs[(w * 64 + ml) * 3 + 2] = den[j];
    }
  }
  __syncthreads();
  if (tid < 64) {                  // merge the 8 waves' partial softmax states
    float M = __builtin_inff();
    #pragma unroll
    for (int ww = 0; ww < 8; ++ww) M = fminf(M, Qs[(ww * 64 + tid) * 3]);
    float Ns = 0.f, Ds = 0.f;
    #pragma unroll
    for (int ww = 0; ww < 8; ++ww) {
      const float f = __builtin_amdgcn_exp2f(CC * (M - Qs[(ww * 64 + tid) * 3]));
      Ns = fmaf(Qs[(ww * 64 + tid) * 3 + 1], f, Ns);
      Ds = fmaf(Qs[(ww * 64 + tid) * 3 + 2], f, Ds);
    }
    out[(size_t)b * NPTS + m0 + tid] = Ns / Ds + bo[0];
  }
}

extern "C" void kernel_launch(void* const* d_in, const int* in_sizes, int n_in,
                              void* d_out, int out_size, void* d_ws, size_t ws_size,
                              hipStream_t stream)
{
  const float* coords_f = (const float*)d_in[0];
  const float* values_f = (const float*)d_in[1];
  const float* coords_t = (const float*)d_in[2];
  const float* Wk1 = (const float*)d_in[3];
  const float* bk1 = (const float*)d_in[4];
  const float* Wk2 = (const float*)d_in[5];
  const float* bk2 = (const float*)d_in[6];
  const float* Wq1 = (const float*)d_in[7];
  const float* bq1 = (const float*)d_in[8];
  const float* Wq2 = (const float*)d_in[9];
  const float* bq2 = (const float*)d_in[10];
  const float* Wv1 = (const float*)d_in[11];
  const float* bv1 = (const float*)d_in[12];
  const float* Wv2 = (const float*)d_in[13];
  const float* bv2 = (const float*)d_in[14];
  const float* Wo  = (const float*)d_in[15];
  const float* bo  = (const float*)d_in[16];

  const int B    = in_sizes[0] / (NPTS * 3);
  const int npts = B * NPTS;

  float* Kt  = (float*)d_ws;                       // [B][64][N]
  float* Qt  = Kt + (size_t)B * 64 * NPTS;         // [B][64][M]
  float* VoW = Qt + (size_t)B * 64 * NPTS;         // [B][N]

  feat_kernel<<<npts / 64, 256, 0, stream>>>(coords_f, Wk1, bk1, Wk2, bk2, Kt, npts);
  feat_kernel<<<npts / 64, 256, 0, stream>>>(coords_t, Wq1, bq1, Wq2, bq2, Qt, npts);
  vo_kernel<<<npts / 256, 256, 0, stream>>>(values_f, Wv1, bv1, Wv2, bv2, Wo, VoW, npts);
  attn_kernel<<<B * 64, 512, 0, stream>>>(Kt, Qt, VoW, bo, (float*)d_out);
}

// Round 2
// 1583.444 us; speedup vs baseline: 1.0034x; 1.0034x over previous
//
#include <hip/hip_runtime.h>
#include <math.h>

#define NPTS 4096
#define CC 0.7213475204444817f   // log2(e)/2 : exp(-s^2/2) = 2^(-CC*s^2)

__device__ __forceinline__ void gload_lds16(const float* g, float* l) {
  __builtin_amdgcn_global_load_lds(
      (const __attribute__((address_space(1))) void*)g,
      (__attribute__((address_space(3))) void*)l, 16, 0, 0);
}

// ---------------- feature MLP: coords[B,N,3] -> outT[b][h][n] (transposed) ----------------
__global__ __launch_bounds__(256) void feat_kernel(
    const float* __restrict__ coords, const float* __restrict__ W1,
    const float* __restrict__ b1, const float* __restrict__ W2,
    const float* __restrict__ b2, float* __restrict__ outT, int npts)
{
  __shared__ float sW1[3 * 64], sb1[64], sW2[64 * 64], sb2[64];
  const int tid = threadIdx.x;
  for (int i = tid; i < 192; i += 256) sW1[i] = W1[i];
  if (tid < 64) { sb1[tid] = b1[tid]; sb2[tid] = b2[tid]; }
  for (int i = tid; i < 4096; i += 256) sW2[i] = W2[i];
  __syncthreads();

  const int p  = blockIdx.x * 64 + (tid & 63);   // point index (consecutive threads -> consecutive n)
  const int qh = (tid >> 6) * 16;                // h-quarter handled by this thread
  if (p >= npts) return;
  const float c0 = coords[p * 3 + 0], c1 = coords[p * 3 + 1], c2 = coords[p * 3 + 2];

  float hid[64];
  #pragma unroll
  for (int j = 0; j < 64; ++j)
    hid[j] = fmaxf(0.f, fmaf(c0, sW1[j], fmaf(c1, sW1[64 + j], fmaf(c2, sW1[128 + j], sb1[j]))));

  float acc[16];
  #pragma unroll
  for (int h = 0; h < 16; ++h) acc[h] = sb2[qh + h];
  for (int j = 0; j < 64; ++j) {
    const float hj = hid[j];
    const float4* wrow = (const float4*)&sW2[j * 64 + qh];
    #pragma unroll
    for (int hq = 0; hq < 4; ++hq) {
      float4 wv = wrow[hq];
      acc[hq * 4 + 0] = fmaf(hj, wv.x, acc[hq * 4 + 0]);
      acc[hq * 4 + 1] = fmaf(hj, wv.y, acc[hq * 4 + 1]);
      acc[hq * 4 + 2] = fmaf(hj, wv.z, acc[hq * 4 + 2]);
      acc[hq * 4 + 3] = fmaf(hj, wv.w, acc[hq * 4 + 3]);
    }
  }
  const int b = p / NPTS, n = p % NPTS;
  #pragma unroll
  for (int h = 0; h < 16; ++h)
    outT[(size_t)(b * 64 + qh + h) * NPTS + n] = acc[h];
}

// ---------------- Vo kernel: Vo[b,n] = MLP_v(values)[b,n,:] . Wo ----------------
__global__ __launch_bounds__(256) void vo_kernel(
    const float* __restrict__ values, const float* __restrict__ Wv1,
    const float* __restrict__ bv1, const float* __restrict__ Wv2,
    const float* __restrict__ bv2, const float* __restrict__ Wo,
    float* __restrict__ VoOut, int npts)
{
  __shared__ float sWvO[64], sW1[64], sb1[64], sc0;
  const int tid = threadIdx.x;
  if (tid < 64) {
    float a = 0.f;
    for (int h = 0; h < 64; ++h) a = fmaf(Wv2[tid * 64 + h], Wo[h], a);
    sWvO[tid] = a;
    sW1[tid] = Wv1[tid];
    sb1[tid] = bv1[tid];
  } else if (tid == 64) {
    float a = 0.f;
    for (int h = 0; h < 64; ++h) a = fmaf(bv2[h], Wo[h], a);
    sc0 = a;
  }
  __syncthreads();
  const int p = blockIdx.x * 256 + tid;
  if (p >= npts) return;
  const float v = values[p];
  float a = sc0;
  #pragma unroll 8
  for (int j = 0; j < 64; ++j)
    a = fmaf(fmaxf(0.f, fmaf(v, sW1[j], sb1[j])), sWvO[j], a);
  VoOut[p] = a;
}

// ---------------- main attention kernel ----------------
// grid: B*64 blocks (one 64-m tile each), 512 threads (8 waves).
// Grid is exactly 256 blocks on 256 CUs -> 1 block/CU regardless of VGPRs,
// so NO min-waves launch bound: let the allocator use up to 256 VGPRs
// (round-1 lesson: (512,2) capped at 128 VGPR -> 5.5 GB scratch spill traffic).
__global__ __launch_bounds__(512) void attn_kernel(
    const float* __restrict__ Kt, const float* __restrict__ Qt,
    const float* __restrict__ Vo, const float* __restrict__ bo,
    float* __restrict__ out)
{
  __shared__ float Qs[64 * 64];      // [h][m_local]  16 KB (reused for stats at the end)
  __shared__ float Vos[NPTS];        // Vo for this b 16 KB
  __shared__ float Ks[8][2][512];    // [wave][buf][h_local*64 + n_local] 32 KB

  const int b    = blockIdx.x >> 6;
  const int m0   = (blockIdx.x & 63) << 6;
  const int tid  = threadIdx.x;
  const int w    = tid >> 6;
  const int lane = tid & 63;
  const int lm = lane >> 3, ln = lane & 7;

  const float* __restrict__ KtB = Kt + (size_t)b * 64 * NPTS;
  const float* __restrict__ QtB = Qt + (size_t)b * 64 * NPTS;
  const float* __restrict__ VoB = Vo + (size_t)b * NPTS;

  { // stage Q tile and full Vo row into LDS (coalesced float4)
    const int h = tid >> 3, c8 = (tid & 7) * 8;
    *(float4*)&Qs[h * 64 + c8]     = *(const float4*)&QtB[(size_t)h * NPTS + m0 + c8];
    *(float4*)&Qs[h * 64 + c8 + 4] = *(const float4*)&QtB[(size_t)h * NPTS + m0 + c8 + 4];
    *(float4*)&Vos[tid * 8]     = *(const float4*)&VoB[tid * 8];
    *(float4*)&Vos[tid * 8 + 4] = *(const float4*)&VoB[tid * 8 + 4];
  }
  __syncthreads();   // drains vmcnt too -> clean counting below

  float acc[64];
  float Mt[8], num[8], den[8];
  #pragma unroll
  for (int x = 0; x < 64; ++x) acc[x] = 0.f;
  #pragma unroll
  for (int j = 0; j < 8; ++j) { Mt[j] = __builtin_inff(); num[j] = 0.f; den[j] = 0.f; }

  const int noff = w * 64 + (lane & 15) * 4;  // per-lane n column for staging
  const int hrow = lane >> 4;                 // 0..3: row within a 4-row staging instr

  // chunk c: h = (c&7)*8 + {0..7}, n base = (c>>3)*512 + w*64 ; 2 glds instrs of 1KB
  #define ISSUE_K(c_) do { \
    const int I_ = (c_) >> 3, cc_ = (c_) & 7; \
    const float* s_ = KtB + (size_t)(cc_ * 8 + hrow) * NPTS + I_ * 512 + noff; \
    float* d_ = &Ks[w][(c_) & 1][0]; \
    gload_lds16(s_, d_); \
    gload_lds16(s_ + 4 * NPTS, d_ + 256); \
  } while (0)

  ISSUE_K(0);
  ISSUE_K(1);

  for (int I = 0; I < 8; ++I) {          // n-iterations (512 n each)
    #pragma unroll
    for (int cc = 0; cc < 8; ++cc) {     // h-chunks (8 rows each)
      const int c = I * 8 + cc;
      if (c < 63) asm volatile("s_waitcnt vmcnt(2)" ::: "memory");
      else        asm volatile("s_waitcnt vmcnt(0)" ::: "memory");
      __builtin_amdgcn_sched_barrier(0);
      const float* __restrict__ Kw = &Ks[w][cc & 1][ln * 8];
      const float* __restrict__ Qh = &Qs[(cc * 8) * 64 + lm * 8];
      #pragma unroll
      for (int hh = 0; hh < 8; ++hh) {
        float q[8], k[8];
        *(float4*)&q[0] = *(const float4*)(Qh + hh * 64);
        *(float4*)&q[4] = *(const float4*)(Qh + hh * 64 + 4);
        *(float4*)&k[0] = *(const float4*)(Kw + hh * 64);
        *(float4*)&k[4] = *(const float4*)(Kw + hh * 64 + 4);
        #pragma unroll
        for (int j = 0; j < 8; ++j) {
          #pragma unroll
          for (int i = 0; i < 8; ++i)
            acc[j * 8 + i] += fabsf(k[i] - q[j]);   // v_sub + v_add |src|
        }
      }
      if (c + 2 < 64) ISSUE_K(c + 2);
    }

    { // epilogue for iteration I: online softmax update (min of t = s^2)
      float vo[8];
      const int vb = I * 512 + w * 64 + ln * 8;
      *(float4*)&vo[0] = *(const float4*)&Vos[vb];
      *(float4*)&vo[4] = *(const float4*)&Vos[vb + 4];
      #pragma unroll
      for (int j = 0; j < 8; ++j) {
        float t[8];
        #pragma unroll
        for (int i = 0; i < 8; ++i) t[i] = acc[j * 8 + i] * acc[j * 8 + i];
        float rmin = fminf(fminf(fminf(t[0], t[1]), fminf(t[2], t[3])),
                           fminf(fminf(t[4], t[5]), fminf(t[6], t[7])));
        rmin = fminf(rmin, __shfl_xor(rmin, 1));
        rmin = fminf(rmin, __shfl_xor(rmin, 2));
        rmin = fminf(rmin, __shfl_xor(rmin, 4));
        const float nM = fminf(Mt[j], rmin);
        const float sc = __builtin_amdgcn_exp2f(CC * (nM - Mt[j])); // inf start -> 0
        num[j] *= sc; den[j] *= sc; Mt[j] = nM;
        const float base = CC * nM;
        #pragma unroll
        for (int i = 0; i < 8; ++i) {
          const float wgt = __builtin_amdgcn_exp2f(fmaf(-CC, t[i], base));
          den[j] += wgt;
          num[j] = fmaf(wgt, vo[i], num[j]);
          acc[j * 8 + i] = 0.f;
        }
      }
    }
  }

  // reduce num/den over the 8 ln-lanes sharing each m (Mt already uniform)
  #pragma unroll
  for (int j = 0; j < 8; ++j) {
    #pragma unroll
    for (int off = 1; off < 8; off <<= 1) {
      num[j] += __shfl_xor(num[j], off);
      den[j] += __shfl_xor(den[j], off);
    }
  }
  __syncthreads();                 // everyone done reading Qs/Ks
  if (ln == 0) {
    #pragma unroll
    for (int j = 0; j < 8; ++j) {
      const int ml = lm * 8 + j;
      Qs[(w * 64 + ml) * 3 + 0] = Mt[j];
      Qs[(w * 64 + ml) * 3 + 1] = num[j];
      Qs[(w * 64 + ml) * 3 + 2] = den[j];
    }
  }
  __syncthreads();
  if (tid < 64) {                  // merge the 8 waves' partial softmax states
    float M = __builtin_inff();
    #pragma unroll
    for (int ww = 0; ww < 8; ++ww) M = fminf(M, Qs[(ww * 64 + tid) * 3]);
    float Ns = 0.f, Ds = 0.f;
    #pragma unroll
    for (int ww = 0; ww < 8; ++ww) {
      const float f = __builtin_amdgcn_exp2f(CC * (M - Qs[(ww * 64 + tid) * 3]));
      Ns = fmaf(Qs[(ww * 64 + tid) * 3 + 1], f, Ns);
      Ds = fmaf(Qs[(ww * 64 + tid) * 3 + 2], f, Ds);
    }
    out[(size_t)b * NPTS + m0 + tid] = Ns / Ds + bo[0];
  }
}

extern "C" void kernel_launch(void* const* d_in, const int* in_sizes, int n_in,
                              void* d_out, int out_size, void* d_ws, size_t ws_size,
                              hipStream_t stream)
{
  const float* coords_f = (const float*)d_in[0];
  const float* values_f = (const float*)d_in[1];
  const float* coords_t = (const float*)d_in[2];
  const float* Wk1 = (const float*)d_in[3];
  const float* bk1 = (const float*)d_in[4];
  const float* Wk2 = (const float*)d_in[5];
  const float* bk2 = (const float*)d_in[6];
  const float* Wq1 = (const float*)d_in[7];
  const float* bq1 = (const float*)d_in[8];
  const float* Wq2 = (const float*)d_in[9];
  const float* bq2 = (const float*)d_in[10];
  const float* Wv1 = (const float*)d_in[11];
  const float* bv1 = (const float*)d_in[12];
  const float* Wv2 = (const float*)d_in[13];
  const float* bv2 = (const float*)d_in[14];
  const float* Wo  = (const float*)d_in[15];
  const float* bo  = (const float*)d_in[16];

  const int B    = in_sizes[0] / (NPTS * 3);
  const int npts = B * NPTS;

  float* Kt  = (float*)d_ws;                       // [B][64][N]
  float* Qt  = Kt + (size_t)B * 64 * NPTS;         // [B][64][M]
  float* VoW = Qt + (size_t)B * 64 * NPTS;         // [B][N]

  feat_kernel<<<npts / 64, 256, 0, stream>>>(coords_f, Wk1, bk1, Wk2, bk2, Kt, npts);
  feat_kernel<<<npts / 64, 256, 0, stream>>>(coords_t, Wq1, bq1, Wq2, bq2, Qt, npts);
  vo_kernel<<<npts / 256, 256, 0, stream>>>(values_f, Wv1, bv1, Wv2, bv2, Wo, VoW, npts);
  attn_kernel<<<B * 64, 512, 0, stream>>>(Kt, Qt, VoW, bo, (float*)d_out);
}